// Round 12
// baseline (239.672 us; speedup 1.0000x reference)
//
#include <hip/hip_runtime.h>

// LIF neuron scan: x[T,B,D] f32, v0[D] f32 -> spikes[T,B,D] f32.
// T=512, B=64, D=1024. tau=0.5 (exact mul), threshold=1.0, v_reset=0.0.
//
// R1:  1 thread/chain, unroll16            -> ~80us, 2.5 TB/s
// R4/R6: ping-pong / triple-buf + schedbar -> ~77us. inert.
// R7:  4x TLP (T-chunks + 64-step warmup)  -> ~80us. inert.
// R11: 4x width (dwordx4 per thread)       -> ~85us. inert.
//   => compiler collapses every structure to W~1 outstanding load/wave
//      (per-step full memory round-trip; vmcnt(0) drains stores too).
// R12: inline-asm loads + HAND-COUNTED s_waitcnt vmcnt(8/16) (never 0,
//      never waits on stores), ping-pong 8-step register blocks, distance 1.
//      sched_barrier(0) after each wait (guide rule #18). The compiler
//      cannot re-serialize what it cannot see.

constexpr int T_STEPS  = 512;
constexpr int B_DIM    = 64;
constexpr int D_DIM    = 1024;
constexpr int N_CHAIN  = B_DIM * D_DIM;      // 65536 chains
constexpr int VEC      = 4;                  // chains per thread (16B vector)
constexpr int NT_VEC   = N_CHAIN / VEC;      // 16384 vector columns
constexpr int C_CHUNKS = 4;
constexpr int T_CHUNK  = T_STEPS / C_CHUNKS; // 128
constexpr int K_WARM   = 64;                 // speculative warm-up steps
constexpr int U        = 8;                  // timesteps per register block

typedef float v4f __attribute__((ext_vector_type(4)));

// Counted wait + scheduler fence (rule #18: consumes must not hoist past it).
#define WAITV(N)                                                      \
    do {                                                              \
        asm volatile("s_waitcnt vmcnt(" #N ")" ::: "memory");         \
        __builtin_amdgcn_sched_barrier(0);                            \
    } while (0)

// Issue U async 16B loads; compiler cannot reorder/serialize them.
__device__ __forceinline__ void load8(v4f (&buf)[U],
                                      const v4f* __restrict__ xp, int tbase) {
#pragma unroll
    for (int k = 0; k < U; ++k)
        asm volatile("global_load_dwordx4 %0, %1, off"
                     : "=v"(buf[k])
                     : "v"(xp + (size_t)(tbase + k) * NT_VEC)
                     : "memory");
}

// Serial LIF over one U-block. ST=false: warm-up (state only, no stores).
template<bool ST>
__device__ __forceinline__ void cons8(const v4f (&buf)[U], float (&v)[VEC],
                                      v4f* __restrict__ op, int tbase) {
#pragma unroll
    for (int k = 0; k < U; ++k) {
        const float xs[VEC] = {buf[k].x, buf[k].y, buf[k].z, buf[k].w};
        float ss[VEC];
#pragma unroll
        for (int i = 0; i < VEC; ++i) {
            float vi = v[i] * 0.5f + xs[i];   // exact: tau = 0.5
            const bool sp = (vi >= 1.0f);
            ss[i] = sp ? 1.0f : 0.0f;
            v[i]  = sp ? 0.0f : vi;
        }
        if (ST) {
            v4f s;
            s.x = ss[0]; s.y = ss[1]; s.z = ss[2]; s.w = ss[3];
            __builtin_nontemporal_store(s, op + (size_t)(tbase + k) * NT_VEC);
        }
    }
}

__global__ __launch_bounds__(256, 1)   // full VGPR budget: no spill of 2x32-reg buffers
void lif_scan_kernel(const float* __restrict__ x,
                     const float* __restrict__ v0,
                     float* __restrict__ out) {
    const int col   = ((blockIdx.x & 63) << 8) + threadIdx.x;  // 0..16383
    const int chunk = blockIdx.x >> 6;                         // 0..3 (block-uniform)

    const v4f* xp = (const v4f*)x   + col;
    v4f*       op = (v4f*)      out + col;
    const int  d0 = (col * VEC) & (D_DIM - 1);

    float v[VEC];
    v4f bA[U], bB[U];
    const int tstart = chunk * T_CHUNK;

    if (chunk == 0) {
        const v4f vi = *(const v4f*)(v0 + d0);     // exact start
        v[0] = vi.x; v[1] = vi.y; v[2] = vi.z; v[3] = vi.w;
        load8(bA, xp, tstart);                     // m0 in flight
    } else {
#pragma unroll
        for (int i = 0; i < VEC; ++i) v[i] = 0.0f; // speculative start
        // Warm-up: 8 blocks, no stores -> steady vmcnt(8) (only next loads newer).
        const int tw = tstart - K_WARM;
        load8(bA, xp, tw);                         // w0 in flight
        for (int p = 0; p < 4; ++p) {
            load8(bB, xp, tw + (2 * p + 1) * U); WAITV(8);
            cons8<false>(bA, v, op, 0);
            load8(bA, xp, tw + (2 * p + 2) * U); WAITV(8);   // p=3 loads m0
            cons8<false>(bB, v, op, 0);
        }
        // exits with bA = m0 in flight (tw + 8U == tstart)
    }

    // Main: 16 store-blocks. vmcnt budget: newer-than-block-k ops =
    // stores_{k-1}(8) + loads_{k+1}(8) = 16 in steady state; 8 at the seams.
    load8(bB, xp, tstart + 1 * U);  WAITV(8);   cons8<true>(bA, v, op, tstart);
    load8(bA, xp, tstart + 2 * U);  WAITV(16);  cons8<true>(bB, v, op, tstart + 1 * U);
    for (int p = 1; p < 7; ++p) {
        load8(bB, xp, tstart + (2 * p + 1) * U); WAITV(16);
        cons8<true>(bA, v, op, tstart + (2 * p) * U);
        load8(bA, xp, tstart + (2 * p + 2) * U); WAITV(16);
        cons8<true>(bB, v, op, tstart + (2 * p + 1) * U);
    }
    load8(bB, xp, tstart + 15 * U); WAITV(16);  cons8<true>(bA, v, op, tstart + 14 * U);
    WAITV(8);                                   cons8<true>(bB, v, op, tstart + 15 * U);
}

extern "C" void kernel_launch(void* const* d_in, const int* in_sizes, int n_in,
                              void* d_out, int out_size, void* d_ws, size_t ws_size,
                              hipStream_t stream) {
    const float* x   = (const float*)d_in[0];
    const float* v0  = (const float*)d_in[1];
    float*       out = (float*)d_out;

    dim3 block(256);
    dim3 grid(C_CHUNKS * (NT_VEC / 256));   // 4 x 64 = 256 blocks, 1024 waves
    hipLaunchKernelGGL(lif_scan_kernel, grid, block, 0, stream, x, v0, out);
}